// Round 9
// baseline (315.475 us; speedup 1.0000x reference)
//
#include <hip/hip_runtime.h>

typedef _Float16 half8 __attribute__((ext_vector_type(8)));
typedef float f32x4 __attribute__((ext_vector_type(4)));

#define HH 64
#define WW 64
#define HW 4096
#define COUT 256
#define NROWS 12      // staged input rows [rowbase, rowbase+11]
#define XROW 65       // px slots per staged row
#define SGSTRIDE 12480  // bytes per 8-ch subgroup in Xs: 12*65*16

// Raw barrier: flush LDS (lgkmcnt) but do NOT drain vmcnt.
__device__ __forceinline__ void bar_sync() {
    asm volatile("s_waitcnt lgkmcnt(0)" ::: "memory");
    __builtin_amdgcn_s_barrier();
    asm volatile("" ::: "memory");
}

// ---------------------------------------------------------------------------
// Kernel 1: blend circle weights -> f16 in PADDED-K MFMA A layout.
// Padded K': octet o4 = 4*kl + q (kl 0..95, q 0..3); g = o4/12 (8-ch group),
// tt = o4%12 (tap; 9..11 = zero padding).  Frag for (kl, tm, lane=rr|q<<4):
// 16 B at wp[((kl*16+tm)*64+lane)*8], element j = channel g*8+j.
// ---------------------------------------------------------------------------
__global__ __launch_bounds__(256) void prep_weights(const float* __restrict__ weight,
                                                    _Float16* __restrict__ wp) {
    const int t = blockIdx.x * 256 + threadIdx.x;   // 0..98303
    const int lane = t & 63;
    const int tm   = (t >> 6) & 15;
    const int kl   = t >> 10;              // 0..95
    const int rr = lane & 15, q = lane >> 4;
    const int o4 = 4 * kl + q;
    const int g  = o4 / 12;
    const int tt = o4 - g * 12;            // tap 0..11 (9..11 pad)
    const int o  = tm * 16 + rr;
    half8 v;
    #pragma unroll
    for (int j = 0; j < 8; ++j) v[j] = (_Float16)0.0f;
    if (tt < 9) {
        const float Af = 0.70710678118654752f;
        const float Bf = 1.0f - Af;
        const float* wb = weight + ((size_t)o * 256 + g * 8) * 9;
        #pragma unroll
        for (int j = 0; j < 8; ++j) {
            const float* w = wb + j * 9;
            float r;
            switch (tt) {
                case 0:  r = Af*(Af*w[0]+Bf*w[1]) + Bf*(Af*w[3]+Bf*w[4]); break;
                case 1:  r = w[1]; break;
                case 2:  r = Af*(Bf*w[1]+Af*w[2]) + Bf*(Bf*w[4]+Af*w[5]); break;
                case 3:  r = w[3]; break;
                case 4:  r = w[4]; break;
                case 5:  r = w[5]; break;
                case 6:  r = Bf*(Af*w[3]+Bf*w[4]) + Af*(Af*w[6]+Bf*w[7]); break;
                case 7:  r = w[7]; break;
                default: r = Bf*(Bf*w[4]+Af*w[5]) + Af*(Bf*w[7]+Af*w[8]); break;
            }
            v[j] = (_Float16)r;
        }
    }
    *(half8*)&wp[((size_t)(kl * 16 + tm) * 64 + lane) * 8] = v;
}

// ---------------------------------------------------------------------------
// Kernel 2: register-resident-B implicit GEMM. 256 blocks x 512 thr (8 waves).
// Wave = px-quarter Q (0..3) x k-parity p (0..1); acc[16] = all 256 m for 16 px.
// Each thread's gather result IS its MFMA B-fragment (B never enters LDS).
// Stage s (16 ch, 6 ksteps): [bar] write Xs | next loads [bar] 3 parity
// ksteps: gather(static tap rotation) -> 16 A b128 global loads -> 16 MFMA.
// Padding: taps 9..11 have zero weights -> res = 0 (uniform, no divergence).
// ---------------------------------------------------------------------------
__global__ __launch_bounds__(512, 2) void dcn_main(
        const float* __restrict__ x, const float* __restrict__ off,
        const float* __restrict__ msk, const _Float16* __restrict__ wp,
        const float* __restrict__ bias, float* __restrict__ out) {
    __shared__ char smem[32768];   // Xs[0..24959]; epilogue: f32 scratch 32KB
    const char* XsB = (const char*)smem;
    char* XsW = smem;

    const int tid  = threadIdx.x;
    const int wv   = tid >> 6;
    const int lane = tid & 63;
    const int q    = lane >> 4, rr = lane & 15;

    const int Q = wv & 3;          // px-quarter
    const int p = wv >> 2;         // k-parity
    const int px = Q * 16 + rr;    // this thread's pixel (B-frag col)

    const int bid = blockIdx.x;
    const int xcd = bid & 7;
    const int b   = xcd >> 1;
    const int h   = ((xcd & 1) << 5) | (bid >> 3);

    const int rowbase = min(max(h - 5, 0), HH - NROWS);
    const float* xb = x + (size_t)b * 256 * HW;
    const char* wpB = (const char*)wp;

    // ---- staging slots: 3 per thread, lane-contiguous (R6-proven) ---------
    int SGk[3], GOFF[3], XA[3];
    #pragma unroll
    for (int k = 0; k < 3; ++k) {
        int slot = k * 512 + tid;             // 0..1535
        int sg   = slot / 768;
        int rem  = slot - sg * 768;
        int row  = rem >> 6, spx = rem & 63;
        SGk[k]  = sg;
        GOFF[k] = (rowbase + row) * 64 + spx;
        XA[k]   = ((sg * NROWS + row) * XROW + spx) * 16;   // byte offset
    }

    // ---- per-thread tap params: rotation r=0..2 -> tap = 4r + q -----------
    _Float16 W00h[3], W01h[3], W10h[3], W11h[3];
    int AYp[3], GPp[3];
    #pragma unroll
    for (int r = 0; r < 3; ++r) {
        const int tap = 4 * r + q;
        if (tap < 9) {
            int ki = tap / 3, kj = tap - 3 * ki;
            const float* offp = off + (size_t)b * 18 * HW + h * 64 + px;
            float dy = offp[(2 * tap) * HW];
            float dx = offp[(2 * tap + 1) * HW];
            float mv = msk[(size_t)b * 9 * HW + (size_t)tap * HW + h * 64 + px];
            float py  = (float)(h - 1 + ki) + dy;
            float pxf = (float)(px - 1 + kj) + dx;
            float y0f = floorf(py), x0f = floorf(pxf);
            float ly = py - y0f, lx = pxf - x0f;
            float hy = 1.0f - ly, hx = 1.0f - lx;
            int y0 = (int)y0f, x0 = (int)x0f;
            int y1 = y0 + 1, x1 = x0 + 1;
            bool vy0 = (y0 >= 0) && (y0 < HH), vy1 = (y1 >= 0) && (y1 < HH);
            bool vx0 = (x0 >= 0) && (x0 < WW), vx1 = (x1 >= 0) && (x1 < WW);
            int cy0 = min(max(y0, 0), HH - 1), cy1 = min(max(y1, 0), HH - 1);
            int cx0 = min(max(x0, 0), WW - 1), cx1 = min(max(x1, 0), WW - 1);
            W00h[r] = (_Float16)((vy0 && vx0) ? hy * hx * mv : 0.0f);
            W01h[r] = (_Float16)((vy0 && vx1) ? hy * lx * mv : 0.0f);
            W10h[r] = (_Float16)((vy1 && vx0) ? ly * hx * mv : 0.0f);
            W11h[r] = (_Float16)((vy1 && vx1) ? ly * lx * mv : 0.0f);
            int ry0 = min(max(cy0 - rowbase, 0), NROWS - 1);
            int ry1 = min(max(cy1 - rowbase, 0), NROWS - 1);
            bool useG = (vy0 && (cy0 < rowbase || cy0 > rowbase + NROWS - 1))
                     || (vy1 && (cy1 < rowbase || cy1 > rowbase + NROWS - 1));
            AYp[r] = ((ry0 * XROW + cx0) * 16) | (((ry1 * XROW + cx0) * 16) << 16);
            GPp[r] = cy0 | (cy1 << 6) | (cx0 << 12) | (cx1 << 18)
                   | ((cx1 - cx0) << 24) | (useG ? (1u << 31) : 0);
        } else {   // padding tap: zero weights -> res = 0, safe addr 0
            W00h[r] = (_Float16)0.0f; W01h[r] = (_Float16)0.0f;
            W10h[r] = (_Float16)0.0f; W11h[r] = (_Float16)0.0f;
            AYp[r] = 0; GPp[r] = 0;
        }
    }

    f32x4 acc[16];
    #pragma unroll
    for (int t = 0; t < 16; ++t) acc[t] = (f32x4)0.0f;

    // ---- preload stage 0 staging values -----------------------------------
    float R[3][8];
    #pragma unroll
    for (int k = 0; k < 3; ++k) {
        const float* pp = xb + (size_t)(SGk[k] * 8) * HW + GOFF[k];
        #pragma unroll
        for (int j = 0; j < 8; ++j) R[k][j] = pp[j * HW];
    }

#define KSTEP(KL, RSEL, SGO, GB) do {                                         \
    const int ayp_ = AYp[RSEL]; const int gpp_ = GPp[RSEL];                   \
    const int a0_ = (ayp_ & 0xffff) + (SGO) * SGSTRIDE;                       \
    const int a1_ = ((int)((unsigned)ayp_ >> 16)) + (SGO) * SGSTRIDE;         \
    const int dxo_ = (gpp_ & (1 << 24)) ? 16 : 0;                             \
    half8 c00 = *(const half8*)(XsB + a0_);                                   \
    half8 c01 = *(const half8*)(XsB + a0_ + dxo_);                            \
    half8 c10 = *(const half8*)(XsB + a1_);                                   \
    half8 c11 = *(const half8*)(XsB + a1_ + dxo_);                            \
    half8 res = c00 * W00h[RSEL] + c01 * W01h[RSEL]                           \
              + c10 * W10h[RSEL] + c11 * W11h[RSEL];                          \
    if (gpp_ < 0) {                                                           \
        int cy0_ = gpp_ & 63, cy1_ = (gpp_ >> 6) & 63;                        \
        int cx0_ = (gpp_ >> 12) & 63, cx1_ = (gpp_ >> 18) & 63;               \
        const float* xc_ = xb + (size_t)((GB) * 8) * HW;                      \
        float w0_ = (float)W00h[RSEL], w1_ = (float)W01h[RSEL];               \
        float w2_ = (float)W10h[RSEL], w3_ = (float)W11h[RSEL];               \
        int i00_ = cy0_ * 64 + cx0_, i01_ = cy0_ * 64 + cx1_;                 \
        int i10_ = cy1_ * 64 + cx0_, i11_ = cy1_ * 64 + cx1_;                 \
        _Pragma("unroll")                                                     \
        for (int j = 0; j < 8; ++j) {                                         \
            float v_ = w0_ * xc_[i00_] + w1_ * xc_[i01_]                      \
                     + w2_ * xc_[i10_] + w3_ * xc_[i11_];                     \
            res[j] = (_Float16)v_; xc_ += HW;                                 \
        }                                                                     \
    }                                                                         \
    const char* ap_ = wpB + (size_t)(KL) * 16384 + lane * 16;                 \
    half8 af[16];                                                             \
    _Pragma("unroll")                                                         \
    for (int t = 0; t < 16; ++t) af[t] = *(const half8*)(ap_ + t * 1024);     \
    _Pragma("unroll")                                                         \
    for (int t = 0; t < 16; ++t)                                              \
        acc[t] = __builtin_amdgcn_mfma_f32_16x16x32_f16(af[t], res, acc[t],   \
                                                        0, 0, 0);             \
} while (0)

    #pragma unroll 1
    for (int s = 0; s < 16; ++s) {
        bar_sync();   // previous stage's gathers done -> Xs reusable
        // ---- write Xs (16 ch of stage s) from regs ------------------------
        #pragma unroll
        for (int k = 0; k < 3; ++k) {
            half8 v;
            #pragma unroll
            for (int j = 0; j < 8; ++j) v[j] = (_Float16)R[k][j];
            *(half8*)(XsW + XA[k]) = v;
        }
        // ---- issue stage s+1 global loads (stay in flight) ----------------
        if (s < 15) {
            const int cbase = (s + 1) * 16;
            #pragma unroll
            for (int k = 0; k < 3; ++k) {
                const float* pp = xb + (size_t)(cbase + SGk[k] * 8) * HW + GOFF[k];
                #pragma unroll
                for (int j = 0; j < 8; ++j) R[k][j] = pp[j * HW];
            }
        }
        bar_sync();   // Xs ready
        // ---- 3 parity ksteps, static tap rotation / sg / group ------------
        const int kl0 = 6 * s;
        const int g0 = 2 * s, g1 = 2 * s + 1;
        if (p == 0) {
            KSTEP(kl0 + 0, 0, 0, g0);
            KSTEP(kl0 + 2, 2, 0, g0);
            KSTEP(kl0 + 4, 1, 1, g1);
        } else {
            KSTEP(kl0 + 1, 1, 0, g0);
            KSTEP(kl0 + 3, 0, 1, g1);
            KSTEP(kl0 + 5, 2, 1, g1);
        }
    }
#undef KSTEP

    // ---- epilogue: parity-partial reduce via LDS (2 rounds), then store ---
    float* scr = (float*)smem;   // Xs dead; 4 Q x 64 lanes x 8 tiles x 16B = 32KB
    #pragma unroll 1
    for (int rd = 0; rd < 2; ++rd) {
        bar_sync();
        if (p == 1) {
            #pragma unroll
            for (int tt = 0; tt < 8; ++tt)
                *(f32x4*)&scr[((Q * 8 + tt) * 64 + lane) * 4] = acc[rd * 8 + tt];
        }
        bar_sync();
        if (p == 0) {
            #pragma unroll
            for (int tt = 0; tt < 8; ++tt) {
                f32x4 pr = *(const f32x4*)&scr[((Q * 8 + tt) * 64 + lane) * 4];
                #pragma unroll
                for (int e = 0; e < 4; ++e) {
                    int m = (rd * 8 + tt) * 16 + q * 4 + e;
                    out[((size_t)b * COUT + m) * HW + h * 64 + px]
                        = acc[rd * 8 + tt][e] + pr[e] + bias[m];
                }
            }
        }
    }
}

extern "C" void kernel_launch(void* const* d_in, const int* in_sizes, int n_in,
                              void* d_out, int out_size, void* d_ws, size_t ws_size,
                              hipStream_t stream) {
    const float* x      = (const float*)d_in[0];   // [4,256,64,64]
    const float* off    = (const float*)d_in[1];   // [4,18,64,64]
    const float* msk    = (const float*)d_in[2];   // [4,9,64,64]
    const float* weight = (const float*)d_in[3];   // [256,256,3,3]
    const float* bias   = (const float*)d_in[4];   // [256]
    float* out = (float*)d_out;                    // [4,256,64,64]

    _Float16* wp = (_Float16*)d_ws;                // 786432 f16 = 1.57 MB

    prep_weights<<<384, 256, 0, stream>>>(weight, wp);
    dcn_main<<<256, 512, 0, stream>>>(x, off, msk, wp, bias, out);
}